// Round 4
// baseline (141.541 us; speedup 1.0000x reference)
//
#include <hip/hip_runtime.h>
#include <stdint.h>

#define B_ROWS 16384
#define C_CLS  2000
#define C_PAD  2048
#define F_DIM  1024
#define KT     16         // K-tiles of 64
#define TILE_B 16384      // bytes per 128x64 bf16 tile image
#define NRB    64         // gemm row blocks (256 rows each)
#define NCB    8          // gemm col blocks (256 cols each)

typedef float  f32x4  __attribute__((ext_vector_type(4)));
typedef __bf16 bf16x8 __attribute__((ext_vector_type(8)));
typedef unsigned short u16x8 __attribute__((ext_vector_type(8)));

__device__ __forceinline__ unsigned short f2bf(float f) {
    union { float f; uint32_t u; } v; v.f = f;
    uint32_t u = v.u;
    return (unsigned short)((u + 0x7fffu + ((u >> 16) & 1u)) >> 16);  // RNE
}

__device__ __forceinline__ void gl_lds16(const void* g, void* l) {
    __builtin_amdgcn_global_load_lds(
        (const __attribute__((address_space(1))) unsigned int*)g,
        (__attribute__((address_space(3))) unsigned int*)l, 16, 0, 0);
}

// ---- prepass A: feat -> bf16 tiled+swizzled (128x64 tiles), fused fisher ----
__global__ __launch_bounds__(256)
void prepA_kernel(const float* __restrict__ feat, const int* __restrict__ labels,
                  const float* __restrict__ centers,
                  unsigned short* __restrict__ A_pre, float* __restrict__ fisher_part)
{
    const int rt = blockIdx.x >> 2, g = blockIdx.x & 3;
    const int tid = threadIdx.x;
    const int r = tid >> 1, h = tid & 1;
    const int grow = rt * 128 + r;
    const int lab = labels[grow];
    const float* frow = feat    + (size_t)grow * F_DIM;
    const float* crow = centers + (size_t)lab  * F_DIM;
    float facc = 0.f;
    #pragma unroll
    for (int q = 0; q < 4; ++q) {
        const int kt = g * 4 + q;
        char* dst = (char*)(A_pre + (size_t)(rt * KT + kt) * (128 * 64)) + r * 128;
        const int kb = kt * 64 + h * 32;
        #pragma unroll
        for (int c = 0; c < 4; ++c) {
            float4 f0 = *(const float4*)(frow + kb + c * 8);
            float4 f1 = *(const float4*)(frow + kb + c * 8 + 4);
            float4 c0 = *(const float4*)(crow + kb + c * 8);
            float4 c1 = *(const float4*)(crow + kb + c * 8 + 4);
            float d0 = f0.x - c0.x, d1 = f0.y - c0.y, d2 = f0.z - c0.z, d3 = f0.w - c0.w;
            float d4 = f1.x - c1.x, d5 = f1.y - c1.y, d6 = f1.z - c1.z, d7 = f1.w - c1.w;
            facc += d0*d0 + d1*d1 + d2*d2 + d3*d3 + d4*d4 + d5*d5 + d6*d6 + d7*d7;
            u16x8 o = { f2bf(f0.x), f2bf(f0.y), f2bf(f0.z), f2bf(f0.w),
                        f2bf(f1.x), f2bf(f1.y), f2bf(f1.z), f2bf(f1.w) };
            *(u16x8*)(dst + ((h * 64 + c * 16) ^ ((r & 7) << 4))) = o;
        }
    }
    for (int d = 32; d >= 1; d >>= 1) facc += __shfl_xor(facc, d);
    __shared__ float redw[4];
    const int wid = tid >> 6, lane = tid & 63;
    if (lane == 0) redw[wid] = facc;
    __syncthreads();
    if (tid == 0) fisher_part[blockIdx.x] = redw[0] + redw[1] + redw[2] + redw[3];
}

// ---- prepass B: W -> bf16 tiled+swizzled, zero-padded; bias pad folded in ----
__global__ __launch_bounds__(256)
void prepB_kernel(const float* __restrict__ W, const float* __restrict__ bias,
                  unsigned short* __restrict__ B_pre, float* __restrict__ bias_pad)
{
    const int ct = blockIdx.x >> 4, kt = blockIdx.x & 15;
    const int tid = threadIdx.x;
    const int r = tid >> 1, h = tid & 1;
    const int gc = ct * 128 + r;
    char* dst = (char*)(B_pre + (size_t)(ct * KT + kt) * (128 * 64)) + r * 128;
    if (gc < C_CLS) {
        const float* src = W + (size_t)gc * F_DIM + kt * 64 + h * 32;
        #pragma unroll
        for (int c = 0; c < 4; ++c) {
            float4 f0 = *(const float4*)(src + c * 8);
            float4 f1 = *(const float4*)(src + c * 8 + 4);
            u16x8 o = { f2bf(f0.x), f2bf(f0.y), f2bf(f0.z), f2bf(f0.w),
                        f2bf(f1.x), f2bf(f1.y), f2bf(f1.z), f2bf(f1.w) };
            *(u16x8*)(dst + ((h * 64 + c * 16) ^ ((r & 7) << 4))) = o;
        }
    } else {
        u16x8 z = {0,0,0,0,0,0,0,0};
        #pragma unroll
        for (int c = 0; c < 4; ++c)
            *(u16x8*)(dst + ((h * 64 + c * 16) ^ ((r & 7) << 4))) = z;
    }
    if (blockIdx.x < C_PAD / 256) {
        const int i = blockIdx.x * 256 + tid;
        bias_pad[i] = (i < C_CLS) ? bias[i] : -1e30f;
    }
}

// ---- 256x256 MFMA GEMM, 8-phase schedule (T3+T4+T5), sum-exp epilogue ----
__global__ __launch_bounds__(512, 2)
void gemm_kernel(const int* __restrict__ labels, const float* __restrict__ biasp,
                 const unsigned short* __restrict__ A_pre, const unsigned short* __restrict__ B_pre,
                 float* __restrict__ s_part, float* __restrict__ tl_part)
{
    __shared__ alignas(64) char smem[131072];      // 2 x (A 32KB + B 32KB)
    __shared__ float red2[256][4][2];

    const int cpx = gridDim.x >> 3;                 // XCD swizzle: same-XCD blocks share rb
    const int wg = (blockIdx.x & 7) * cpx + (blockIdx.x >> 3);
    const int cb = wg & 7;
    const int rb = wg >> 3;

    const int tid = threadIdx.x;
    const int w = tid >> 6, lane = tid & 63;
    const int l15 = lane & 15, lhi = lane >> 4;
    const int wr = w >> 2, wc = w & 3;

    // staging role: wave w copies half of image (w>>1): 0-1 = A halves, 2-3 = B halves
    const int img = w >> 1, half = w & 1;
    const char* srcbase = (img < 2)
        ? (const char*)A_pre + (size_t)(rb * 2 + img) * KT * TILE_B
        : (const char*)B_pre + (size_t)(cb * 2 + (img - 2)) * KT * TILE_B;
    const int dstoff = ((img < 2) ? img * 16384 : 32768 + (img - 2) * 16384) + half * 8192;
    const int srcoff = half * 8192 + lane * 16;

    // precomputed swizzled ds_read byte offsets (kf toggles bit 6 via XOR)
    int aoff[8], boff[4];
    #pragma unroll
    for (int mi = 0; mi < 8; ++mi) {
        const int r = wr * 128 + mi * 16 + l15;
        aoff[mi] = wr * 16384 + (r & 127) * 128 + ((lhi * 16) ^ ((r & 7) << 4));
    }
    #pragma unroll
    for (int ni = 0; ni < 4; ++ni) {
        const int cc = wc * 64 + ni * 16 + l15;
        boff[ni] = 32768 + (wc >> 1) * 16384 + (cc & 127) * 128 + ((lhi * 16) ^ ((cc & 7) << 4));
    }

    f32x4 acc[8][4];
    #pragma unroll
    for (int mi = 0; mi < 8; ++mi)
        #pragma unroll
        for (int ni = 0; ni < 4; ++ni) acc[mi][ni] = (f32x4){0.f, 0.f, 0.f, 0.f};

    auto STAGE = [&](int kt_, int c_) {
        const char* s = srcbase + (size_t)kt_ * TILE_B + srcoff;
        char* d = smem + c_ * 65536 + dstoff;
        #pragma unroll
        for (int i = 0; i < 8; ++i) gl_lds16(s + i * 1024, d + i * 1024);
    };

#define PHASE(KF, MLO, READBV, LAST) do {                                             \
    bf16x8 af_[4];                                                                    \
    if (READBV) {                                                                     \
        _Pragma("unroll")                                                             \
        for (int ni = 0; ni < 4; ++ni)                                                \
            bv[ni] = *(const bf16x8*)(base + (boff[ni] ^ ((KF) << 6)));               \
    }                                                                                 \
    _Pragma("unroll")                                                                 \
    for (int mi = 0; mi < 4; ++mi)                                                    \
        af_[mi] = *(const bf16x8*)(base + (aoff[(MLO) + mi] ^ ((KF) << 6)));          \
    __builtin_amdgcn_sched_barrier(0);                                                \
    __builtin_amdgcn_s_barrier();                                                     \
    __builtin_amdgcn_s_setprio(1);                                                    \
    _Pragma("unroll")                                                                 \
    for (int mi = 0; mi < 4; ++mi)                                                    \
        _Pragma("unroll")                                                             \
        for (int ni = 0; ni < 4; ++ni)                                                \
            acc[(MLO) + mi][ni] = __builtin_amdgcn_mfma_f32_16x16x32_bf16(            \
                af_[mi], bv[ni], acc[(MLO) + mi][ni], 0, 0, 0);                       \
    __builtin_amdgcn_s_setprio(0);                                                    \
    __builtin_amdgcn_sched_barrier(0);                                                \
    if (LAST) {                                                                       \
        asm volatile("s_waitcnt vmcnt(0)" ::: "memory");                              \
        __builtin_amdgcn_sched_barrier(0);                                            \
    }                                                                                 \
    __builtin_amdgcn_s_barrier();                                                     \
} while (0)

    // prologue: stage tile 0 -> buf0, tile 1 -> buf1; wait only for tile 0
    STAGE(0, 0);
    STAGE(1, 1);
    asm volatile("s_waitcnt vmcnt(8)" ::: "memory");
    __builtin_amdgcn_sched_barrier(0);
    __builtin_amdgcn_s_barrier();

    for (int kt = 0; kt < KT; ++kt) {
        const int c = kt & 1;
        if (kt && kt + 1 < KT) STAGE(kt + 1, c ^ 1);   // prefetch issued early: full-iter cover
        const char* base = smem + c * 65536;
        bf16x8 bv[4];
        PHASE(0, 0, true,  false);
        PHASE(0, 4, false, false);
        PHASE(1, 0, true,  false);
        PHASE(1, 4, false, true);    // boundary: per-wave vmcnt for next tile, then barrier
    }
#undef PHASE

    // epilogue: direct sum-exp (logits bounded; no max needed in fp32)
    float bb[4];
    #pragma unroll
    for (int ni = 0; ni < 4; ++ni)
        bb[ni] = biasp[cb * 256 + wc * 64 + ni * 16 + l15];

    #pragma unroll
    for (int mi = 0; mi < 8; ++mi) {
        #pragma unroll
        for (int j = 0; j < 4; ++j) {
            const int rl = wr * 128 + mi * 16 + lhi * 4 + j;
            const int lab = labels[rb * 256 + rl];
            float sv = 0.f, tv = 0.f;
            #pragma unroll
            for (int ni = 0; ni < 4; ++ni) {
                const float v = acc[mi][ni][j] + bb[ni];
                sv += __expf(v);
                const int gc = cb * 256 + wc * 64 + ni * 16 + l15;
                tv = (gc == lab) ? v : tv;
            }
            #pragma unroll
            for (int d = 1; d < 16; d <<= 1) {
                sv += __shfl_xor(sv, d);
                tv += __shfl_xor(tv, d);
            }
            if (l15 == 0) { red2[rl][wc][0] = sv; red2[rl][wc][1] = tv; }
        }
    }
    __syncthreads();
    if (tid < 256) {
        const float sv = red2[tid][0][0] + red2[tid][1][0] + red2[tid][2][0] + red2[tid][3][0];
        const float tv = red2[tid][0][1] + red2[tid][1][1] + red2[tid][2][1] + red2[tid][3][1];
        const int grow = rb * 256 + tid;
        s_part[(size_t)cb * B_ROWS + grow]  = sv;
        tl_part[(size_t)cb * B_ROWS + grow] = tv;
    }
}

// ---- combine partials across the 8 column blocks, per-row aux loss ----
__global__ __launch_bounds__(256)
void rowcomb_kernel(const float* __restrict__ s_part, const float* __restrict__ tl_part,
                    float* __restrict__ aux_part)
{
    const int row = blockIdx.x * 256 + threadIdx.x;
    float s = 0.f, t = 0.f;
    #pragma unroll
    for (int p = 0; p < NCB; ++p) {
        s += s_part[(size_t)p * B_ROWS + row];
        t += tl_part[(size_t)p * B_ROWS + row];
    }
    float acc = __logf(s) - t;
    for (int d = 32; d >= 1; d >>= 1) acc += __shfl_xor(acc, d);
    __shared__ float red[4];
    const int wid = threadIdx.x >> 6, lane = threadIdx.x & 63;
    if (lane == 0) red[wid] = acc;
    __syncthreads();
    if (threadIdx.x == 0) aux_part[blockIdx.x] = red[0] + red[1] + red[2] + red[3];
}

__global__ __launch_bounds__(256)
void final_kernel(const float* __restrict__ fisher_part, const float* __restrict__ aux_part,
                  float* __restrict__ out)
{
    const int tid = threadIdx.x;
    float acc = fisher_part[tid] + fisher_part[256 + tid];
    if (tid < 64) acc += aux_part[tid];
    for (int d = 32; d >= 1; d >>= 1) acc += __shfl_xor(acc, d);
    __shared__ float red[4];
    const int wid = tid >> 6, lane = tid & 63;
    if (lane == 0) red[wid] = acc;
    __syncthreads();
    if (tid == 0) out[0] = (red[0] + red[1] + red[2] + red[3]) * (1.0f / (float)B_ROWS);
}

extern "C" void kernel_launch(void* const* d_in, const int* in_sizes, int n_in,
                              void* d_out, int out_size, void* d_ws, size_t ws_size,
                              hipStream_t stream)
{
    (void)in_sizes; (void)n_in; (void)out_size; (void)ws_size;
    const float* feat    = (const float*)d_in[0];
    const int*   labels  = (const int*)  d_in[1];
    const float* centers = (const float*)d_in[2];
    const float* W       = (const float*)d_in[3];
    const float* bias    = (const float*)d_in[4];
    float* out = (float*)d_out;
    char* ws = (char*)d_ws;

    const size_t szA    = (size_t)128 * KT * 128 * 64 * 2;  // 33,554,432
    const size_t szB    = (size_t)16  * KT * 128 * 64 * 2;  //  4,194,304
    const size_t szBias = (size_t)C_PAD * 4;

    unsigned short* A_pre = (unsigned short*)ws;
    unsigned short* B_pre = (unsigned short*)(ws + szA);
    float* bias_pad    = (float*)(ws + szA + szB);
    float* s_part      = (float*)(ws + szA + szB + szBias);
    float* tl_part     = s_part + (size_t)NCB * B_ROWS;
    float* fisher_part = tl_part + (size_t)NCB * B_ROWS;
    float* aux_part    = fisher_part + 512;

    prepA_kernel<<<512, 256, 0, stream>>>(feat, labels, centers, A_pre, fisher_part);
    prepB_kernel<<<256, 256, 0, stream>>>(W, bias, B_pre, bias_pad);
    gemm_kernel<<<NRB * NCB, 512, 0, stream>>>(labels, bias_pad, A_pre, B_pre, s_part, tl_part);
    rowcomb_kernel<<<B_ROWS / 256, 256, 0, stream>>>(s_part, tl_part, aux_part);
    final_kernel<<<1, 256, 0, stream>>>(fisher_part, aux_part, out);
}

// Round 5
// 130.301 us; speedup vs baseline: 1.0863x; 1.0863x over previous
//
#include <hip/hip_runtime.h>
#include <stdint.h>

#define B_ROWS 16384
#define C_CLS  2000
#define C_PAD  2048
#define F_DIM  1024
#define NKT    32            // K-tiles of 32
#define IMG_B  8192          // 128x32 bf16 image bytes
#define NRB    64            // gemm row blocks (256 rows)
#define NCB    8             // gemm col blocks (256 cols)

typedef float  f32x4  __attribute__((ext_vector_type(4)));
typedef __bf16 bf16x8 __attribute__((ext_vector_type(8)));
typedef unsigned short u16x8 __attribute__((ext_vector_type(8)));

__device__ __forceinline__ unsigned short f2bf(float f) {
    union { float f; uint32_t u; } v; v.f = f;
    uint32_t u = v.u;
    return (unsigned short)((u + 0x7fffu + ((u >> 16) & 1u)) >> 16);  // RNE
}

// file/LDS position of 16B chunk c (0..3 = k-slice c*8..+8) of row r (0..127):
// row pairs packed into 128B, XOR-swizzled -> ds_read_b128 is 2-way max (free)
__device__ __forceinline__ int chunk_pos(int r, int c) {
    return (r >> 1) * 128 + (((c * 32) + ((r & 1) << 4)) ^ (((r >> 1) & 7) << 4));
}

__device__ __forceinline__ void gl_lds16(const void* g, void* l) {
    __builtin_amdgcn_global_load_lds(
        (const __attribute__((address_space(1))) unsigned int*)g,
        (__attribute__((address_space(3))) unsigned int*)l, 16, 0, 0);
}

// ---- prepass A: feat -> bf16 128x32 images, fused fisher. grid 256 = rt(128) x kh(2)
__global__ __launch_bounds__(256)
void prepA_kernel(const float* __restrict__ feat, const int* __restrict__ labels,
                  const float* __restrict__ centers,
                  unsigned short* __restrict__ A_pre, float* __restrict__ fisher_part)
{
    const int rt = blockIdx.x >> 1, kh = blockIdx.x & 1;
    const int tid = threadIdx.x;
    const int r = tid >> 1, h = tid & 1;
    const int grow = rt * 128 + r;
    const int lab = labels[grow];
    const float* frow = feat    + (size_t)grow * F_DIM;
    const float* crow = centers + (size_t)lab  * F_DIM;
    float facc = 0.f;
    #pragma unroll 4
    for (int q = 0; q < 16; ++q) {
        const int kt = kh * 16 + q;
        char* img = (char*)A_pre + ((size_t)((rt >> 1) * NKT + kt) * 2 + (rt & 1)) * IMG_B;
        const int kb = kt * 32 + h * 16;
        #pragma unroll
        for (int cc = 0; cc < 2; ++cc) {
            float4 f0 = *(const float4*)(frow + kb + cc * 8);
            float4 f1 = *(const float4*)(frow + kb + cc * 8 + 4);
            float4 c0 = *(const float4*)(crow + kb + cc * 8);
            float4 c1 = *(const float4*)(crow + kb + cc * 8 + 4);
            float d0 = f0.x - c0.x, d1 = f0.y - c0.y, d2 = f0.z - c0.z, d3 = f0.w - c0.w;
            float d4 = f1.x - c1.x, d5 = f1.y - c1.y, d6 = f1.z - c1.z, d7 = f1.w - c1.w;
            facc += d0*d0 + d1*d1 + d2*d2 + d3*d3 + d4*d4 + d5*d5 + d6*d6 + d7*d7;
            u16x8 o = { f2bf(f0.x), f2bf(f0.y), f2bf(f0.z), f2bf(f0.w),
                        f2bf(f1.x), f2bf(f1.y), f2bf(f1.z), f2bf(f1.w) };
            *(u16x8*)(img + chunk_pos(r, h * 2 + cc)) = o;
        }
    }
    for (int d = 32; d >= 1; d >>= 1) facc += __shfl_xor(facc, d);
    __shared__ float redw[4];
    const int wid = tid >> 6, lane = tid & 63;
    if (lane == 0) redw[wid] = facc;
    __syncthreads();
    if (tid == 0) fisher_part[blockIdx.x] = redw[0] + redw[1] + redw[2] + redw[3];
}

// ---- prepass B: W -> bf16 128x32 images, zero-pad; bias pad folded. grid 128 = ct(16) x ktg(8)
__global__ __launch_bounds__(256)
void prepB_kernel(const float* __restrict__ W, const float* __restrict__ bias,
                  unsigned short* __restrict__ B_pre, float* __restrict__ bias_pad)
{
    const int ct = blockIdx.x >> 3, ktg = blockIdx.x & 7;
    const int tid = threadIdx.x;
    const int r = tid >> 1, h = tid & 1;
    const int gc = ct * 128 + r;
    #pragma unroll
    for (int q = 0; q < 4; ++q) {
        const int kt = ktg * 4 + q;
        char* img = (char*)B_pre + ((size_t)((ct >> 1) * NKT + kt) * 2 + (ct & 1)) * IMG_B;
        if (gc < C_CLS) {
            const float* src = W + (size_t)gc * F_DIM + kt * 32 + h * 16;
            #pragma unroll
            for (int cc = 0; cc < 2; ++cc) {
                float4 f0 = *(const float4*)(src + cc * 8);
                float4 f1 = *(const float4*)(src + cc * 8 + 4);
                u16x8 o = { f2bf(f0.x), f2bf(f0.y), f2bf(f0.z), f2bf(f0.w),
                            f2bf(f1.x), f2bf(f1.y), f2bf(f1.z), f2bf(f1.w) };
                *(u16x8*)(img + chunk_pos(r, h * 2 + cc)) = o;
            }
        } else {
            u16x8 z = {0,0,0,0,0,0,0,0};
            #pragma unroll
            for (int cc = 0; cc < 2; ++cc)
                *(u16x8*)(img + chunk_pos(r, h * 2 + cc)) = z;
        }
    }
    if (blockIdx.x < C_PAD / 256) {
        const int i = blockIdx.x * 256 + tid;
        bias_pad[i] = (i < C_CLS) ? bias[i] : -1e30f;
    }
}

// ---- 256x256 MFMA GEMM, BK=32, 3-buffer counted-vmcnt pipeline, sum-exp epilogue ----
__global__ __launch_bounds__(512, 2)
void gemm_kernel(const int* __restrict__ labels, const float* __restrict__ biasp,
                 const unsigned short* __restrict__ A_pre, const unsigned short* __restrict__ B_pre,
                 float* __restrict__ s_part, float* __restrict__ tl_part)
{
    __shared__ alignas(64) char smem[98304];         // 3 buffers x (A 16KB + B 16KB)
    __shared__ float red2[256][4][2];

    const int cpx = gridDim.x >> 3;                  // XCD swizzle: same-XCD blocks share rb
    const int wg = (blockIdx.x & 7) * cpx + (blockIdx.x >> 3);
    const int cb = wg & 7;
    const int rb = wg >> 3;

    const int tid = threadIdx.x;
    const int w = tid >> 6, lane = tid & 63;
    const int l15 = lane & 15, lhi = lane >> 4;
    const int wr = w >> 2, wc = w & 3;

    const char* Asrc = (const char*)A_pre + (size_t)rb * NKT * 2 * IMG_B;  // 16KB per kt
    const char* Bsrc = (const char*)B_pre + (size_t)cb * NKT * 2 * IMG_B;

    // swizzled ds_read byte offsets within a buffer
    int aoff[8], boff[4];
    #pragma unroll
    for (int mi = 0; mi < 8; ++mi) {
        const int r = mi * 16 + l15;
        aoff[mi] = wr * IMG_B + chunk_pos(r, lhi);
    }
    #pragma unroll
    for (int ni = 0; ni < 4; ++ni) {
        const int rr = (wc & 1) * 64 + ni * 16 + l15;
        boff[ni] = 16384 + (wc >> 1) * IMG_B + chunk_pos(rr, lhi);
    }

    f32x4 acc[8][4];
    #pragma unroll
    for (int mi = 0; mi < 8; ++mi)
        #pragma unroll
        for (int ni = 0; ni < 4; ++ni) acc[mi][ni] = (f32x4){0.f, 0.f, 0.f, 0.f};

    auto STAGE = [&](int kt_, int bufoff_) {
        const char* sa = Asrc + (size_t)kt_ * 16384 + tid * 16;
        const char* sb = Bsrc + (size_t)kt_ * 16384 + tid * 16;
        char* d = smem + bufoff_ + tid * 16;
        gl_lds16(sa,        d);
        gl_lds16(sa + 8192, d + 8192);
        gl_lds16(sb,        d + 16384);
        gl_lds16(sb + 8192, d + 24576);
    };

    auto COMPUTE = [&](int bufoff_) {
        const char* base = smem + bufoff_;
        bf16x8 af[8], bv[4];
        #pragma unroll
        for (int ni = 0; ni < 4; ++ni) bv[ni] = *(const bf16x8*)(base + boff[ni]);
        #pragma unroll
        for (int mi = 0; mi < 8; ++mi) af[mi] = *(const bf16x8*)(base + aoff[mi]);
        __builtin_amdgcn_s_setprio(1);
        #pragma unroll
        for (int mi = 0; mi < 8; ++mi)
            #pragma unroll
            for (int ni = 0; ni < 4; ++ni)
                acc[mi][ni] = __builtin_amdgcn_mfma_f32_16x16x32_bf16(af[mi], bv[ni], acc[mi][ni], 0, 0, 0);
        __builtin_amdgcn_s_setprio(0);
    };

    // prologue: tiles 0,1 into buffers 0,1
    STAGE(0, 0);
    STAGE(1, 32768);
    int bo = 0, so = 65536;
    for (int kt = 0; kt < NKT - 2; ++kt) {
        STAGE(kt + 2, so);                               // 2-iteration prefetch depth
        asm volatile("s_waitcnt vmcnt(8)" ::: "memory"); // counted: kt+1,kt+2 stay in flight
        __builtin_amdgcn_sched_barrier(0);
        __builtin_amdgcn_s_barrier();
        __builtin_amdgcn_sched_barrier(0);
        COMPUTE(bo);
        __builtin_amdgcn_sched_barrier(0);
        __builtin_amdgcn_s_barrier();                    // protect buffer reuse next iter
        bo = (bo == 65536) ? 0 : bo + 32768;
        so = (so == 65536) ? 0 : so + 32768;
    }
    // kt = NKT-2
    asm volatile("s_waitcnt vmcnt(4)" ::: "memory");
    __builtin_amdgcn_sched_barrier(0);
    __builtin_amdgcn_s_barrier();
    __builtin_amdgcn_sched_barrier(0);
    COMPUTE(bo);
    __builtin_amdgcn_sched_barrier(0);
    __builtin_amdgcn_s_barrier();
    bo = (bo == 65536) ? 0 : bo + 32768;
    // kt = NKT-1
    asm volatile("s_waitcnt vmcnt(0)" ::: "memory");
    __builtin_amdgcn_sched_barrier(0);
    __builtin_amdgcn_s_barrier();
    __builtin_amdgcn_sched_barrier(0);
    COMPUTE(bo);

    // epilogue: direct sum-exp (logits bounded; no max needed in fp32)
    float bb[4];
    #pragma unroll
    for (int ni = 0; ni < 4; ++ni)
        bb[ni] = biasp[cb * 256 + wc * 64 + ni * 16 + l15];

    #pragma unroll
    for (int mi = 0; mi < 8; ++mi) {
        #pragma unroll
        for (int j = 0; j < 4; ++j) {
            const int rl = wr * 128 + mi * 16 + lhi * 4 + j;
            const int lab = labels[rb * 256 + rl];
            float sv = 0.f, tv = 0.f;
            #pragma unroll
            for (int ni = 0; ni < 4; ++ni) {
                const float v = acc[mi][ni][j] + bb[ni];
                sv += __expf(v);
                const int gc = cb * 256 + wc * 64 + ni * 16 + l15;
                tv = (gc == lab) ? v : tv;
            }
            #pragma unroll
            for (int d = 1; d < 16; d <<= 1) {
                sv += __shfl_xor(sv, d);
                tv += __shfl_xor(tv, d);
            }
            if (l15 == 0) { red2[rl][wc][0] = sv; red2[rl][wc][1] = tv; }
        }
    }
    __syncthreads();
    if (tid < 256) {
        const float sv = red2[tid][0][0] + red2[tid][1][0] + red2[tid][2][0] + red2[tid][3][0];
        const float tv = red2[tid][0][1] + red2[tid][1][1] + red2[tid][2][1] + red2[tid][3][1];
        const int grow = rb * 256 + tid;
        s_part[(size_t)cb * B_ROWS + grow]  = sv;
        tl_part[(size_t)cb * B_ROWS + grow] = tv;
    }
}

// ---- combine partials across the 8 column blocks, per-row aux loss ----
__global__ __launch_bounds__(256)
void rowcomb_kernel(const float* __restrict__ s_part, const float* __restrict__ tl_part,
                    float* __restrict__ aux_part)
{
    const int row = blockIdx.x * 256 + threadIdx.x;
    float s = 0.f, t = 0.f;
    #pragma unroll
    for (int p = 0; p < NCB; ++p) {
        s += s_part[(size_t)p * B_ROWS + row];
        t += tl_part[(size_t)p * B_ROWS + row];
    }
    float acc = __logf(s) - t;
    for (int d = 32; d >= 1; d >>= 1) acc += __shfl_xor(acc, d);
    __shared__ float red[4];
    const int wid = threadIdx.x >> 6, lane = threadIdx.x & 63;
    if (lane == 0) red[wid] = acc;
    __syncthreads();
    if (threadIdx.x == 0) aux_part[blockIdx.x] = red[0] + red[1] + red[2] + red[3];
}

__global__ __launch_bounds__(256)
void final_kernel(const float* __restrict__ fisher_part, const float* __restrict__ aux_part,
                  float* __restrict__ out)
{
    const int tid = threadIdx.x;
    float acc = fisher_part[tid];          // 256 partials
    if (tid < 64) acc += aux_part[tid];
    for (int d = 32; d >= 1; d >>= 1) acc += __shfl_xor(acc, d);
    __shared__ float red[4];
    const int wid = tid >> 6, lane = tid & 63;
    if (lane == 0) red[wid] = acc;
    __syncthreads();
    if (tid == 0) out[0] = (red[0] + red[1] + red[2] + red[3]) * (1.0f / (float)B_ROWS);
}

extern "C" void kernel_launch(void* const* d_in, const int* in_sizes, int n_in,
                              void* d_out, int out_size, void* d_ws, size_t ws_size,
                              hipStream_t stream)
{
    (void)in_sizes; (void)n_in; (void)out_size; (void)ws_size;
    const float* feat    = (const float*)d_in[0];
    const int*   labels  = (const int*)  d_in[1];
    const float* centers = (const float*)d_in[2];
    const float* W       = (const float*)d_in[3];
    const float* bias    = (const float*)d_in[4];
    float* out = (float*)d_out;
    char* ws = (char*)d_ws;

    const size_t szA    = (size_t)NRB * NKT * 2 * IMG_B;   // 33,554,432
    const size_t szB    = (size_t)NCB * NKT * 2 * IMG_B;   //  4,194,304
    const size_t szBias = (size_t)C_PAD * 4;

    unsigned short* A_pre = (unsigned short*)ws;
    unsigned short* B_pre = (unsigned short*)(ws + szA);
    float* bias_pad    = (float*)(ws + szA + szB);
    float* s_part      = (float*)(ws + szA + szB + szBias);
    float* tl_part     = s_part + (size_t)NCB * B_ROWS;
    float* fisher_part = tl_part + (size_t)NCB * B_ROWS;
    float* aux_part    = fisher_part + 512;

    prepA_kernel<<<256, 256, 0, stream>>>(feat, labels, centers, A_pre, fisher_part);
    prepB_kernel<<<128, 256, 0, stream>>>(W, bias, B_pre, bias_pad);
    gemm_kernel<<<NRB * NCB, 512, 0, stream>>>(labels, bias_pad, A_pre, B_pre, s_part, tl_part);
    rowcomb_kernel<<<B_ROWS / 256, 256, 0, stream>>>(s_part, tl_part, aux_part);
    final_kernel<<<1, 256, 0, stream>>>(fisher_part, aux_part, out);
}